// Round 3
// baseline (552.617 us; speedup 1.0000x reference)
//
#include <hip/hip_runtime.h>
#include <math.h>

namespace {

typedef short short8 __attribute__((ext_vector_type(8)));
typedef float f32x4 __attribute__((ext_vector_type(4)));

constexpr int kB = 4, kT = 2048, kD = 512, kE = 4, kC = 1024, kHE = 512,
              kO = 512, kEC = 4096;

__device__ __forceinline__ unsigned short f2bf(float f) {
    unsigned int u = __float_as_uint(f);
    u += 0x7fffu + ((u >> 16) & 1u);   // RNE
    return (unsigned short)(u >> 16);
}

__device__ __forceinline__ float gelu_exact(float v) {
    return 0.5f * v * (1.0f + erff(v * 0.70710678118654752f));
}

#define GLDS16(g, l)                                                      \
    __builtin_amdgcn_global_load_lds(                                     \
        (const __attribute__((address_space(1))) unsigned int*)(g),       \
        (__attribute__((address_space(3))) unsigned int*)(l), 16, 0, 0)

// ---------------------------------------------------------------------------
// Batched transpose+cast: in[z] is R x Cc fp32 -> out[z] is Cc x R bf16.
__global__ __launch_bounds__(256)
void transpose_cast(const float* __restrict__ in, unsigned short* __restrict__ out,
                    int R, int Cc, long long sIn, long long sOut)
{
    __shared__ float tile[32][33];
    const int z = blockIdx.z;
    const float* ip = in + (long long)z * sIn;
    unsigned short* op = out + (long long)z * sOut;
    const int c0 = blockIdx.x * 32, r0 = blockIdx.y * 32;
    const int tx = threadIdx.x & 31, ty = threadIdx.x >> 5;  // ty 0..7
#pragma unroll
    for (int i = 0; i < 4; ++i) {
        const int r = ty + i * 8;
        tile[r][tx] = ip[(size_t)(r0 + r) * Cc + c0 + tx];
    }
    __syncthreads();
#pragma unroll
    for (int i = 0; i < 4; ++i) {
        const int c = ty + i * 8;
        op[(size_t)(c0 + c) * R + r0 + tx] = f2bf(tile[tx][c]);
    }
}

// Plain elementwise fp32 -> bf16 (n multiple of 4).
__global__ __launch_bounds__(256)
void cast_bf16(const float* __restrict__ in, unsigned short* __restrict__ out,
               long long n)
{
    const long long i = ((long long)blockIdx.x * blockDim.x + threadIdx.x) * 4;
    if (i < n) {
        const float4 v = *(const float4*)&in[i];
        unsigned short o[4] = {f2bf(v.x), f2bf(v.y), f2bf(v.z), f2bf(v.w)};
        *(uint2*)&out[i] = *(const uint2*)o;
    }
}

__global__ __launch_bounds__(256)
void fill_zero(float* __restrict__ p, long long n4)
{
    const long long i = (long long)blockIdx.x * blockDim.x + threadIdx.x;
    if (i < n4) *(float4*)&p[i * 4] = make_float4(0.f, 0.f, 0.f, 0.f);
}

// out[b][t][o] = b2[o];  n4 = total/4, O=512 divides every row.
__global__ __launch_bounds__(256)
void fill_bias(float* __restrict__ p, const float* __restrict__ b2, long long n4)
{
    const long long i = (long long)blockIdx.x * blockDim.x + threadIdx.x;
    if (i < n4) {
        const int col = (int)((i * 4) & (kO - 1));
        *(float4*)&p[i * 4] = *(const float4*)&b2[col];
    }
}

// ---------------------------------------------------------------------------
// MFMA GEMM (m97 structure, 128x128 tile, BK=64), with:
//  - XCD-contiguous block swizzle (flat%8 owns a contiguous work range)
//  - optional split-K (kSplit blocks accumulate via fp32 atomics, MODE 2)
//  - optional fp32 A operand (AF32: load+cvt+ds_write staging), for S2
// B element (n,k) at ((k>>bShift)*N + n)<<bShift | (k & mask); bShift=log2(K)
// degenerates to n*K+k; bShift=10 handles yT's [e][O][C] segmented layout.
// MODE: 0 = bf16 store, 1 = bf16 gelu(acc+bias[n]), 2 = fp32 atomic add.
template <int MODE, bool AF32>
__global__ __launch_bounds__(256)
void mfma_gemm(const void* __restrict__ Aall,
               const unsigned short* __restrict__ Ball,
               const float* __restrict__ biasAll,
               void* __restrict__ Call,
               int M, int N, int Kext, int KA,
               long long sA, long long sB, long long sC,
               int zModA, int zModB, int zModBias, int biasStride,
               int bShift, int kSplit)
{
    __shared__ unsigned short As[128 * 64];
    __shared__ unsigned short Bs[128 * 64];

    // --- XCD-contiguous swizzle: flat -> (z, my, nx) ---
    const int nt = gridDim.x, mt = gridDim.y;
    const int flat = blockIdx.x + nt * (blockIdx.y + mt * blockIdx.z);
    const int total = nt * mt * gridDim.z;
    const int work = (flat & 7) * (total >> 3) + (flat >> 3);
    const int z = work / (mt * nt);
    const int rem = work - z * (mt * nt);
    const int my = rem / nt;
    const int nx = rem - my * nt;

    const int zz = z / kSplit;             // batch index
    const int ks = z - zz * kSplit;        // K-split index
    const int kBeg = ks * Kext;

    const unsigned short* Ab =
        (const unsigned short*)Aall + (long long)(zz % zModA) * sA;
    const unsigned short* Bb = Ball + (long long)(zz % zModB) * sB;
    const float* bias =
        (MODE == 1) ? biasAll + (long long)(zz % zModBias) * biasStride : nullptr;

    const int t = threadIdx.x;
    const int lane = t & 63;
    const int w = t >> 6;           // wave 0..3
    const int wrow = w * 32;        // staging row block per wave
    const int l8r = lane >> 3;      // row within 8-row staging group
    const int l8c = (lane & 7) * 8; // k element offset (8 bf16 = 16 B)
    const int row0 = my * 128;
    const int col0 = nx * 128;

    const int wm = (w >> 1) * 64;   // wave's 64x64 quadrant
    const int wn = (w & 1) * 64;
    const int fr = lane & 15;
    const int fq = (lane >> 4) * 8;

    f32x4 acc[4][4] = {};

    for (int k0 = 0; k0 < Kext; k0 += 64) {
        if (AF32) {
            const float* Af = (const float*)Aall + (long long)(zz % zModA) * sA;
#pragma unroll
            for (int r = 0; r < 8; ++r) {
                const int f = r * 256 + t;      // float4 id, 16 per 64-k row
                const int row = f >> 4;
                const int k4 = (f & 15) * 4;
                const float4 v = *(const float4*)
                    &Af[(size_t)(row0 + row) * KA + kBeg + k0 + k4];
                unsigned short o[4] = {f2bf(v.x), f2bf(v.y), f2bf(v.z), f2bf(v.w)};
                *(uint2*)&As[row * 64 + k4] = *(const uint2*)o;
            }
        }
#pragma unroll
        for (int r = 0; r < 4; ++r) {
            if (!AF32) {
                const int ar = row0 + wrow + r * 8 + l8r;
                GLDS16(Ab + (size_t)ar * KA + (kBeg + k0 + l8c),
                       &As[(wrow + r * 8) * 64]);
            }
            const int bn = col0 + wrow + r * 8 + l8r;
            const int gk = kBeg + k0 + l8c;
            const size_t boff =
                (((size_t)(gk >> bShift) * N + bn) << bShift) +
                (gk & ((1u << bShift) - 1u));
            GLDS16(Bb + boff, &Bs[(wrow + r * 8) * 64]);
        }
        __syncthreads();
#pragma unroll
        for (int kk = 0; kk < 2; ++kk) {
            short8 af[4], bf[4];
#pragma unroll
            for (int i = 0; i < 4; ++i)
                af[i] = *(const short8*)&As[(wm + i * 16 + fr) * 64 + kk * 32 + fq];
#pragma unroll
            for (int j = 0; j < 4; ++j)
                bf[j] = *(const short8*)&Bs[(wn + j * 16 + fr) * 64 + kk * 32 + fq];
#pragma unroll
            for (int i = 0; i < 4; ++i)
#pragma unroll
                for (int j = 0; j < 4; ++j)
                    acc[i][j] = __builtin_amdgcn_mfma_f32_16x16x32_bf16(
                        af[i], bf[j], acc[i][j], 0, 0, 0);
        }
        __syncthreads();
    }

    // Epilogue. C/D layout: col = lane&15, row = (lane>>4)*4 + reg  [m89/m91].
    const long long cz = (long long)zz * sC;
#pragma unroll
    for (int i = 0; i < 4; ++i) {
        const int rowb = row0 + wm + i * 16 + (lane >> 4) * 4;
#pragma unroll
        for (int j = 0; j < 4; ++j) {
            const int col = col0 + wn + j * 16 + fr;
            const float bv = (MODE == 1) ? bias[col] : 0.0f;
#pragma unroll
            for (int r = 0; r < 4; ++r) {
                const float v = acc[i][j][r];
                const size_t idx = (size_t)cz + (size_t)(rowb + r) * N + col;
                if (MODE == 0)
                    ((unsigned short*)Call)[idx] = f2bf(v);
                else if (MODE == 1)
                    ((unsigned short*)Call)[idx] = f2bf(gelu_exact(v + bv));
                else
                    unsafeAtomicAdd(&((float*)Call)[idx], v);
            }
        }
    }
}

}  // namespace

extern "C" void kernel_launch(void* const* d_in, const int* in_sizes, int n_in,
                              void* d_out, int out_size, void* d_ws, size_t ws_size,
                              hipStream_t stream)
{
    const float* x    = (const float*)d_in[0];  // (B,T,D)
    const float* mask = (const float*)d_in[1];  // (B,T,EC)
    const float* comb = (const float*)d_in[2];  // (B,T,EC)
    const float* w1   = (const float*)d_in[3];  // (E,D,HE)
    const float* b1   = (const float*)d_in[4];  // (E,HE)
    const float* w2   = (const float*)d_in[5];  // (E,HE,O)
    const float* b2   = (const float*)d_in[6];  // (O,)
    float* out = (float*)d_out;                 // (B,T,O) fp32

    // Workspace layout (bytes): 124 MB total.
    //  regA   64 MB  : maskT [B][EC][T] bf16, then combB [B][T][EC] bf16
    //  xT      8 MB  : [B][D][T] bf16
    //  w1T     2 MB  : [E][HE][D] bf16
    //  w2T     2 MB  : [E][O][HE] bf16
    //  xdF    32 MB  : [B][EC][D] fp32 (S1 split-K atomic target);
    //                  first 16 MB reused as yT [B][E][O][C] bf16 after S2
    //  h      16 MB  : [B*E][C][HE] bf16
    unsigned short* regA  = (unsigned short*)d_ws;
    unsigned short* xT    = regA + 33554432;
    unsigned short* w1T   = xT + 4194304;
    unsigned short* w2T   = w1T + 1048576;
    float*          xdF   = (float*)(w2T + 1048576);
    unsigned short* h     = (unsigned short*)(xdF + 8388608);
    unsigned short* maskT = regA;
    unsigned short* combB = regA;
    unsigned short* yT    = (unsigned short*)xdF;

    dim3 blk(256);

    // --- conversions ---
    transpose_cast<<<dim3(kEC / 32, kT / 32, kB), blk, 0, stream>>>(
        mask, maskT, kT, kEC, (long long)kT * kEC, (long long)kT * kEC);
    transpose_cast<<<dim3(kD / 32, kT / 32, kB), blk, 0, stream>>>(
        x, xT, kT, kD, (long long)kT * kD, (long long)kT * kD);
    transpose_cast<<<dim3(kHE / 32, kD / 32, kE), blk, 0, stream>>>(
        w1, w1T, kD, kHE, (long long)kD * kHE, (long long)kD * kHE);
    transpose_cast<<<dim3(kO / 32, kHE / 32, kE), blk, 0, stream>>>(
        w2, w2T, kHE, kO, (long long)kHE * kO, (long long)kHE * kO);
    fill_zero<<<dim3(8388608 / 4 / 256), blk, 0, stream>>>(xdF, 8388608LL / 4);

    // --- S1 (split-K x2): xdF[b][ec][d] += maskT[b]*xT[b]^T, fp32 atomics ---
    mfma_gemm<2, false><<<dim3(kD / 128, kEC / 128, kB * 2), blk, 0, stream>>>(
        maskT, xT, nullptr, xdF, kEC, kD, kT / 2, kT,
        (long long)kEC * kT, (long long)kD * kT, (long long)kEC * kD,
        kB, kB, 1, 0, 11, 2);

    // comb cast (reuses maskT's region; stream-ordered after S1)
    cast_bf16<<<dim3(33554432 / 4 / 256), blk, 0, stream>>>(
        comb, combB, 33554432LL);

    // --- S2: h[g][c][he] = gelu(xdF[g]*w1T[e]^T + b1[e])  (A is fp32) ---
    mfma_gemm<1, true><<<dim3(kHE / 128, kC / 128, kB * kE), blk, 0, stream>>>(
        xdF, w1T, b1, h, kC, kHE, kD, kD,
        (long long)kC * kD, (long long)kHE * kD, (long long)kC * kHE,
        kB * kE, kE, kE, kHE, 9, 1);

    // --- S3 (swapped): yT[g][o][c] = w2T[e]*h[g]^T  (overwrites xdF region) ---
    mfma_gemm<0, false><<<dim3(kC / 128, kO / 128, kB * kE), blk, 0, stream>>>(
        w2T, h, nullptr, yT, kO, kC, kHE, kHE,
        (long long)kO * kHE, (long long)kC * kHE, (long long)kO * kC,
        kE, kB * kE, 1, 0, 9, 1);

    // --- S4 (split-K x4): out += combB[b]*yT[b]^T, atomics onto bias fill ---
    fill_bias<<<dim3(4194304 / 4 / 256), blk, 0, stream>>>(out, b2, 4194304LL / 4);
    mfma_gemm<2, false><<<dim3(kO / 128, kT / 128, kB * 4), blk, 0, stream>>>(
        combB, yT, b2, out, kT, kO, kEC / 4, kEC,
        (long long)kT * kEC, (long long)kE * kO * kC, (long long)kT * kO,
        kB, kB, 1, 0, 10, 4);
}

// Round 4
// 515.326 us; speedup vs baseline: 1.0724x; 1.0724x over previous
//
#include <hip/hip_runtime.h>
#include <math.h>

namespace {

typedef short short8 __attribute__((ext_vector_type(8)));
typedef float f32x4 __attribute__((ext_vector_type(4)));

constexpr int kB = 4, kT = 2048, kD = 512, kE = 4, kC = 1024, kHE = 512,
              kO = 512, kEC = 4096;

__device__ __forceinline__ unsigned short f2bf(float f) {
    unsigned int u = __float_as_uint(f);
    u += 0x7fffu + ((u >> 16) & 1u);   // RNE
    return (unsigned short)(u >> 16);
}

__device__ __forceinline__ float gelu_exact(float v) {
    return 0.5f * v * (1.0f + erff(v * 0.70710678118654752f));
}

#define GLDS16(g, l)                                                      \
    __builtin_amdgcn_global_load_lds(                                     \
        (const __attribute__((address_space(1))) unsigned int*)(g),       \
        (__attribute__((address_space(3))) unsigned int*)(l), 16, 0, 0)

// ---------------------------------------------------------------------------
// Batched transpose+cast: in[z] is R x Cc fp32 -> out[z] is Cc x R bf16.
__global__ __launch_bounds__(256)
void transpose_cast(const float* __restrict__ in, unsigned short* __restrict__ out,
                    int R, int Cc, long long sIn, long long sOut)
{
    __shared__ float tile[32][33];
    const int z = blockIdx.z;
    const float* ip = in + (long long)z * sIn;
    unsigned short* op = out + (long long)z * sOut;
    const int c0 = blockIdx.x * 32, r0 = blockIdx.y * 32;
    const int tx = threadIdx.x & 31, ty = threadIdx.x >> 5;  // ty 0..7
#pragma unroll
    for (int i = 0; i < 4; ++i) {
        const int r = ty + i * 8;
        tile[r][tx] = ip[(size_t)(r0 + r) * Cc + c0 + tx];
    }
    __syncthreads();
#pragma unroll
    for (int i = 0; i < 4; ++i) {
        const int c = ty + i * 8;
        op[(size_t)(c0 + c) * R + r0 + tx] = f2bf(tile[tx][c]);
    }
}

// ---------------------------------------------------------------------------
// MFMA GEMM, 256x128 tile, BK=64, 512 threads = 8 waves (each a 64x64 quad).
//   C[z] = A[MxK, k-contig] * B[NxK, k-contig]^T
// Intensity 85 FLOP/staged-byte (vs 64 for 128x128) — staging-BW is the wall.
// XCD-contiguous swizzle; optional split-K (fp32 atomics, MODE 2).
// B element (n,k) at ((k>>bShift)*N + n)<<bShift | (k & mask); bShift=log2(K)
// degenerates to n*K+k; bShift=10 handles yT's [e][O][C] segmented layout.
// MODE: 0 = bf16 store, 1 = bf16 gelu(acc+bias[n]), 2 = fp32 atomic add.
// TAIL (grid-stride, after epilogue, disjoint buffers, 256-block grids only):
//   1 = cast 33.5M fp32 (tailSrc) -> bf16 (tailDst)       [comb -> combB]
//   2 = fill 4.19M fp32 (tailDst) with 512-float pattern  [out  <- b2   ]
template <int MODE, int TAIL>
__global__ __launch_bounds__(512)
void mfma_gemm(const unsigned short* __restrict__ Aall,
               const unsigned short* __restrict__ Ball,
               const float* __restrict__ biasAll,
               void* __restrict__ Call,
               const float* __restrict__ tailSrc,
               void* __restrict__ tailDst,
               int M, int N, int Kext,
               long long sA, long long sB, long long sC,
               int zModA, int zModB, int zModBias, int biasStride,
               int bShift, int kSplit, int KA)
{
    __shared__ unsigned short As[256 * 64];
    __shared__ unsigned short Bs[128 * 64];

    // --- XCD-contiguous swizzle: flat -> (z, my, nx) ---
    const int nt = gridDim.x, mt = gridDim.y;
    const int flat = blockIdx.x + nt * (blockIdx.y + mt * blockIdx.z);
    const int total = nt * mt * gridDim.z;
    const int work = (flat & 7) * (total >> 3) + (flat >> 3);
    const int z = work / (mt * nt);
    const int rem = work - z * (mt * nt);
    const int my = rem / nt;
    const int nx = rem - my * nt;

    const int zz = z / kSplit;        // batch index
    const int ks = z - zz * kSplit;   // K-split index
    const int kBeg = ks * Kext;

    const unsigned short* Ab = Aall + (long long)(zz % zModA) * sA;
    const unsigned short* Bb = Ball + (long long)(zz % zModB) * sB;
    const float* bias =
        (MODE == 1) ? biasAll + (long long)(zz % zModBias) * biasStride : nullptr;

    const int t = threadIdx.x;
    const int lane = t & 63;
    const int w = t >> 6;            // wave 0..7
    const int l8r = lane >> 3;       // row within 8-row staging group
    const int l8c = (lane & 7) * 8;  // k element offset (8 bf16 = 16 B)
    const int row0 = my * 256;
    const int col0 = nx * 128;

    const int wm = (w >> 1) * 64;    // wave quad: 4 rows x 2 cols of 64x64
    const int wn = (w & 1) * 64;
    const int fr = lane & 15;
    const int fq = (lane >> 4) * 8;

    f32x4 acc[4][4] = {};

    for (int k0 = 0; k0 < Kext; k0 += 64) {
#pragma unroll
        for (int r = 0; r < 4; ++r) {   // A: 256 rows, 8 waves x 4 instrs x 8 rows
            const int ar = row0 + w * 32 + r * 8 + l8r;
            GLDS16(Ab + (size_t)ar * KA + (kBeg + k0 + l8c),
                   &As[(w * 32 + r * 8) * 64]);
        }
#pragma unroll
        for (int r = 0; r < 2; ++r) {   // B: 128 rows, 8 waves x 2 instrs x 8 rows
            const int bn = col0 + w * 16 + r * 8 + l8r;
            const int gk = kBeg + k0 + l8c;
            const size_t boff =
                (((size_t)(gk >> bShift) * N + bn) << bShift) +
                (gk & ((1u << bShift) - 1u));
            GLDS16(Bb + boff, &Bs[(w * 16 + r * 8) * 64]);
        }
        __syncthreads();
#pragma unroll
        for (int kk = 0; kk < 2; ++kk) {
            short8 af[4], bf[4];
#pragma unroll
            for (int i = 0; i < 4; ++i)
                af[i] = *(const short8*)&As[(wm + i * 16 + fr) * 64 + kk * 32 + fq];
#pragma unroll
            for (int j = 0; j < 4; ++j)
                bf[j] = *(const short8*)&Bs[(wn + j * 16 + fr) * 64 + kk * 32 + fq];
#pragma unroll
            for (int i = 0; i < 4; ++i)
#pragma unroll
                for (int j = 0; j < 4; ++j)
                    acc[i][j] = __builtin_amdgcn_mfma_f32_16x16x32_bf16(
                        af[i], bf[j], acc[i][j], 0, 0, 0);
        }
        __syncthreads();
    }

    // Epilogue. C/D layout: col = lane&15, row = (lane>>4)*4 + reg  [m89/m91].
    const long long cz = (long long)zz * sC;
#pragma unroll
    for (int i = 0; i < 4; ++i) {
        const int rowb = row0 + wm + i * 16 + (lane >> 4) * 4;
#pragma unroll
        for (int j = 0; j < 4; ++j) {
            const int col = col0 + wn + j * 16 + fr;
            const float bv = (MODE == 1) ? bias[col] : 0.0f;
#pragma unroll
            for (int r = 0; r < 4; ++r) {
                const float v = acc[i][j][r];
                const size_t idx = (size_t)cz + (size_t)(rowb + r) * N + col;
                if (MODE == 0)
                    ((unsigned short*)Call)[idx] = f2bf(v);
                else if (MODE == 1)
                    ((unsigned short*)Call)[idx] = f2bf(gelu_exact(v + bv));
                else
                    unsafeAtomicAdd(&((float*)Call)[idx], v);
            }
        }
    }

    // Grid-stride tails (131072 threads over 256-block grids).
    if (TAIL == 1) {
        const long long tid = (long long)flat * 512 + t;
        const float4* src4 = (const float4*)tailSrc;
        uint2* dst2 = (uint2*)tailDst;
#pragma unroll 4
        for (int i = 0; i < 64; ++i) {          // 8,388,608 float4s
            const long long p = tid + (long long)i * 131072;
            const float4 v = src4[p];
            unsigned short o[4] = {f2bf(v.x), f2bf(v.y), f2bf(v.z), f2bf(v.w)};
            dst2[p] = *(const uint2*)o;
        }
    } else if (TAIL == 2) {
        const long long tid = (long long)flat * 512 + t;
        const int col = (int)((tid * 4) & (kO - 1));
        const float4 bv = *(const float4*)&tailSrc[col];
        float4* dst4 = (float4*)tailDst;
#pragma unroll
        for (int i = 0; i < 8; ++i)             // 1,048,576 float4s
            dst4[tid + (long long)i * 131072] = bv;
    }
}

}  // namespace

extern "C" void kernel_launch(void* const* d_in, const int* in_sizes, int n_in,
                              void* d_out, int out_size, void* d_ws, size_t ws_size,
                              hipStream_t stream)
{
    const float* x    = (const float*)d_in[0];  // (B,T,D)
    const float* mask = (const float*)d_in[1];  // (B,T,EC)
    const float* comb = (const float*)d_in[2];  // (B,T,EC)
    const float* w1   = (const float*)d_in[3];  // (E,D,HE)
    const float* b1   = (const float*)d_in[4];  // (E,HE)
    const float* w2   = (const float*)d_in[5];  // (E,HE,O)
    const float* b2   = (const float*)d_in[6];  // (O,)
    float* out = (float*)d_out;                 // (B,T,O) fp32

    // Workspace (bf16 elements), 108 MB total:
    //  regA  64 MB : maskT [B][EC][T]; overwritten by combB [B][T][EC] in S2 tail
    //  xT     8 MB : [B][D][T]
    //  w1T    2 MB : [E][HE][D]
    //  w2T    2 MB : [E][O][HE]
    //  xd    16 MB : [B][EC][D]; dead after S2, reused as yT [B][E][O][C] by S3
    //  h     16 MB : [B*E][C][HE]
    unsigned short* regA  = (unsigned short*)d_ws;
    unsigned short* xT    = regA + 33554432;
    unsigned short* w1T   = xT + 4194304;
    unsigned short* w2T   = w1T + 1048576;
    unsigned short* xd    = w2T + 1048576;
    unsigned short* h     = xd + 8388608;
    unsigned short* maskT = regA;
    unsigned short* combB = regA;
    unsigned short* yT    = xd;

    dim3 blk(512);

    // --- conversions ---
    transpose_cast<<<dim3(kEC / 32, kT / 32, kB), dim3(256), 0, stream>>>(
        mask, maskT, kT, kEC, (long long)kT * kEC, (long long)kT * kEC);
    transpose_cast<<<dim3(kD / 32, kT / 32, kB), dim3(256), 0, stream>>>(
        x, xT, kT, kD, (long long)kT * kD, (long long)kT * kD);
    transpose_cast<<<dim3(kHE / 32, kD / 32, kE), dim3(256), 0, stream>>>(
        w1, w1T, kD, kHE, (long long)kD * kHE, (long long)kD * kHE);
    transpose_cast<<<dim3(kO / 32, kHE / 32, kE), dim3(256), 0, stream>>>(
        w2, w2T, kHE, kO, (long long)kHE * kO, (long long)kHE * kO);

    // --- S1: xd[b][ec][d] = maskT[b] * xT[b]^T (bf16 out, no split) ---
    mfma_gemm<0, 0><<<dim3(kD / 128, kEC / 256, kB), blk, 0, stream>>>(
        maskT, xT, nullptr, xd, nullptr, nullptr,
        kEC, kD, kT,
        (long long)kEC * kT, (long long)kD * kT, (long long)kEC * kD,
        kB, kB, 1, 0, 11, 1, kT);

    // --- S2: h[g] = gelu(xd[g]*w1T[e]^T + b1[e]); tail: comb -> combB ---
    mfma_gemm<1, 1><<<dim3(kHE / 128, kC / 256, kB * kE), blk, 0, stream>>>(
        xd, w1T, b1, h, comb, combB,
        kC, kHE, kD,
        (long long)kC * kD, (long long)kHE * kD, (long long)kC * kHE,
        kB * kE, kE, kE, kHE, 9, 1, kD);

    // --- S3: yT[g][o][c] = w2T[e]*h[g]^T; tail: out <- b2 prefill ---
    mfma_gemm<0, 2><<<dim3(kC / 128, kO / 256, kB * kE), blk, 0, stream>>>(
        w2T, h, nullptr, yT, b2, out,
        kO, kC, kHE,
        (long long)kO * kHE, (long long)kC * kHE, (long long)kO * kC,
        kE, kB * kE, 1, 0, 9, 1, kHE);

    // --- S4 (split-K x2): out += combB[b]*yT[b]^T via fp32 atomics ---
    mfma_gemm<2, 0><<<dim3(kO / 128, kT / 256, kB * 2), blk, 0, stream>>>(
        combB, yT, nullptr, out, nullptr, nullptr,
        kT, kO, kEC / 2,
        (long long)kT * kEC, (long long)kE * kO * kC, (long long)kT * kO,
        kB, kB, 1, 0, 10, 2, kEC);
}